// Round 1
// 655.468 us; speedup vs baseline: 1.0060x; 1.0060x over previous
//
#include <hip/hip_runtime.h>
#include <cstdint>
#include <cstddef>

// MoE layer, MI355X. Round 5: double-buffered 2-phase GEMM K-loop
// (prefetch next tile's global_load_lds before computing current; ONE
// __syncthreads per K-step whose implicit vmcnt(0) drain lands after the
// compute phase covered the load latency) + bijective XCD-aware block
// swizzle + setprio around the MFMA cluster.
// T=4096, D=1024, F=4096, E=8, top-2. Padded slots: 9216.

#define D_MODEL 1024
#define D_FF    4096
#define NEXP    8
#define TOKENS  4096
#define SLOTS   8192
#define SLOTSP  9216

typedef __bf16 bf16x8 __attribute__((ext_vector_type(8)));
typedef float  f32x4  __attribute__((ext_vector_type(4)));

static __device__ __forceinline__ unsigned short f2bf(float f) {
  unsigned int u = __float_as_uint(f);
  u += 0x7fffu + ((u >> 16) & 1u);   // RNE
  return (unsigned short)(u >> 16);
}

static __device__ __forceinline__ void async_ld16(const void* g, void* l) {
  __builtin_amdgcn_global_load_lds(
      (const __attribute__((address_space(1))) void*)g,
      (__attribute__((address_space(3))) void*)l, 16, 0, 0);
}

// ---------------- setup kernels ----------------

__global__ void init_kernel(int* __restrict__ tok_list) {
  const int g = blockIdx.x * 256 + threadIdx.x;
  if (g < SLOTSP) tok_list[g] = -1;
}

// one wave per token; no atomics
__global__ __launch_bounds__(256) void router_kernel(
    const float* __restrict__ x, const float* __restrict__ gw,
    float* __restrict__ out_logits, float* __restrict__ out_idx,
    float* __restrict__ out_w)
{
  const int w = threadIdx.x >> 6, lane = threadIdx.x & 63;
  const int t = blockIdx.x * 4 + w;
  float p[NEXP];
#pragma unroll
  for (int e = 0; e < NEXP; ++e) p[e] = 0.f;
  const float* xr = x + (size_t)t * D_MODEL;
#pragma unroll 4
  for (int i = 0; i < D_MODEL / 64; ++i) {
    const int d = i * 64 + lane;
    const float xv = xr[d];
    const float* g = gw + (size_t)d * NEXP;
#pragma unroll
    for (int e = 0; e < NEXP; ++e) p[e] += xv * g[e];
  }
#pragma unroll
  for (int e = 0; e < NEXP; ++e) {
#pragma unroll
    for (int s = 1; s < 64; s <<= 1) p[e] += __shfl_xor(p[e], s, 64);
  }
  if (lane == 0) {
    int i0 = 0;
#pragma unroll
    for (int e = 1; e < NEXP; ++e) if (p[e] > p[i0]) i0 = e;
    int i1 = (i0 == 0) ? 1 : 0;
#pragma unroll
    for (int e = 0; e < NEXP; ++e)
      if (e != i0 && p[e] > p[i1]) i1 = e;
    const float w0 = 1.f / (1.f + __expf(p[i1] - p[i0]));
#pragma unroll
    for (int e = 0; e < NEXP; ++e) out_logits[(size_t)t * NEXP + e] = p[e];
    out_idx[t * 2 + 0] = (float)i0;
    out_idx[t * 2 + 1] = (float)i1;
    out_w[t * 2 + 0] = w0;
    out_w[t * 2 + 1] = 1.f - w0;
  }
}

// single block: histogram + padded offsets + block map + zero cursors
// wsI: [8..16)=cursor [16..25)=po [25]=nb [32..104)=blk_e [128..200)=blk_gr0
__global__ __launch_bounds__(256) void count_offsets_kernel(
    const float* __restrict__ out_idx, int* __restrict__ wsI)
{
  __shared__ int hist[NEXP];
  const int tid = threadIdx.x;
  if (tid < NEXP) hist[tid] = 0;
  if (tid < NEXP) wsI[8 + tid] = 0;   // cursors
  __syncthreads();
  int c[NEXP];
#pragma unroll
  for (int e = 0; e < NEXP; ++e) c[e] = 0;
  for (int p = tid * 32; p < tid * 32 + 32; ++p) c[(int)out_idx[p]]++;
#pragma unroll
  for (int e = 0; e < NEXP; ++e) if (c[e]) atomicAdd(&hist[e], c[e]);
  __syncthreads();
  if (tid == 0) {
    int s = 0, nb = 0;
    for (int e = 0; e < NEXP; ++e) {
      wsI[16 + e] = s;
      const int nblk = (hist[e] + 127) >> 7;
      for (int j = 0; j < nblk; ++j) {
        wsI[32 + nb] = e;
        wsI[128 + nb] = s + j * 128;
        ++nb;
      }
      s += nblk << 7;
    }
    wsI[16 + NEXP] = s;
    wsI[25] = nb;
  }
}

// ballot-aggregated per-wave atomics (~8 per wave instead of 64)
__global__ void scatter_kernel(const float* __restrict__ out_idx,
                               int* __restrict__ cursor,
                               const int* __restrict__ po,
                               int* __restrict__ pair_slot,
                               int* __restrict__ tok_list)
{
  const int p = blockIdx.x * 256 + threadIdx.x;
  const int lane = threadIdx.x & 63;
  const int e = (int)out_idx[p];
  int pos = 0;
#pragma unroll
  for (int e8 = 0; e8 < NEXP; ++e8) {
    const unsigned long long m = __ballot(e == e8);
    if (m) {
      const int leader = __ffsll((long long)m) - 1;
      int base = 0;
      if (lane == leader) base = atomicAdd(&cursor[e8], (int)__popcll(m));
      base = __shfl(base, leader, 64);
      if (e == e8)
        pos = po[e8] + base +
              (int)__popcll(m & ((1ull << lane) - 1ull));
    }
  }
  tok_list[pos] = p >> 1;
  pair_slot[p] = pos;
}

// gather x rows into slot order, f32 -> bf16
__global__ __launch_bounds__(256) void gather_cvt(
    const float* __restrict__ x, const int* __restrict__ tok_list,
    unsigned short* __restrict__ xg)
{
  const int gid = blockIdx.x * 256 + threadIdx.x;
  const int row = gid >> 7, seg = gid & 127;
  const int tok = tok_list[row];
  if (tok < 0) return;
  const float* src = x + (size_t)tok * D_MODEL + seg * 8;
  const float4 a = *(const float4*)(src);
  const float4 b = *(const float4*)(src + 4);
  ushort4 lo = make_ushort4(f2bf(a.x), f2bf(a.y), f2bf(a.z), f2bf(a.w));
  ushort4 hi = make_ushort4(f2bf(b.x), f2bf(b.y), f2bf(b.z), f2bf(b.w));
  unsigned short* d = xg + (size_t)row * D_MODEL + seg * 8;
  *(ushort4*)(d) = lo;
  *(ushort4*)(d + 4) = hi;
}

// src [E][K][N] f32 -> dst [E][N][K] bf16, 64x64 LDS-tiled
__global__ __launch_bounds__(256) void transpose_cvt(
    const float* __restrict__ src, unsigned short* __restrict__ dst,
    int K, int N)
{
  const int e = blockIdx.z;
  const int n0 = blockIdx.x * 64;
  const int k0 = blockIdx.y * 64;
  __shared__ float t[64][65];
  const int c4 = (threadIdx.x & 15) * 4;
  const int r  = threadIdx.x >> 4;
  const float* s = src + (size_t)e * K * N + (size_t)k0 * N + n0;
#pragma unroll
  for (int i = 0; i < 4; ++i) {
    const float4 v = *(const float4*)(s + (size_t)(r + 16 * i) * N + c4);
    t[r + 16 * i][c4 + 0] = v.x;
    t[r + 16 * i][c4 + 1] = v.y;
    t[r + 16 * i][c4 + 2] = v.z;
    t[r + 16 * i][c4 + 3] = v.w;
  }
  __syncthreads();
  unsigned short* d = dst + (size_t)e * N * K + (size_t)n0 * K + k0;
#pragma unroll
  for (int i = 0; i < 4; ++i) {
    const int n = r + 16 * i;
    ushort4 v;
    v.x = f2bf(t[c4 + 0][n]);
    v.y = f2bf(t[c4 + 1][n]);
    v.z = f2bf(t[c4 + 2][n]);
    v.w = f2bf(t[c4 + 3][n]);
    *(ushort4*)(d + (size_t)n * K + c4) = v;
  }
}

// ---------------- MFMA grouped GEMM, BK=64, double-buffered 2-phase ----------------
// LDS layout (per buffer): 128 rows x 8 segs(16B); data seg s of row r lives at
// slot s^(r&7). Staging: thread tid, chunk j: linear slot (j*256+tid) ->
// row=(..)>>3, s_lds=(..)&7, s_glob = s_lds ^ (row&7).
// Fragment: seg = ks2*4+q -> slot = (q ^ (m15&7)) ^ (ks2*4).
// 2-phase: STAGE(buf^1, t+1) issued BEFORE computing buf (load latency hides
// under 32 MFMA); single __syncthreads per K-step supplies vmcnt(0)+barrier.
template <int RELU>
__global__ __launch_bounds__(256) void gemm_mfma(
    const unsigned short* __restrict__ A, const unsigned short* __restrict__ Bt,
    const float* __restrict__ bias, void* __restrict__ Cout,
    const int* __restrict__ wsI, int K, int N)
{
  // bijective XCD-aware swizzle: hw-consecutive blocks -> same XCD gets a
  // contiguous logical chunk (A-panel reuse in that XCD's L2).
  // nwg = gx*gy is divisible by 8 for both launches (2304, 576).
  const int gx = gridDim.x;
  const int nwg = gx * gridDim.y;
  const int cpx = nwg >> 3;
  int f = blockIdx.y * gx + blockIdx.x;
  f = (f & 7) * cpx + (f >> 3);
  const int bx = f % gx;
  const int by = f / gx;

  if (by >= wsI[25]) return;
  const int e   = wsI[32 + by];
  const int gr0 = wsI[128 + by];
  const int col0 = bx * 128;

  __shared__ unsigned short ldsA[2][128 * 64];
  __shared__ unsigned short ldsB[2][128 * 64];

  const int tid = threadIdx.x;
  const int lane = tid & 63;
  const int w = tid >> 6;
  const int wr = w >> 1, wc = w & 1;
  const int m15 = lane & 15, q = lane >> 4;

  f32x4 zero = {0.f, 0.f, 0.f, 0.f};
  f32x4 acc[4][4];
#pragma unroll
  for (int mt = 0; mt < 4; ++mt)
#pragma unroll
    for (int nt = 0; nt < 4; ++nt) acc[mt][nt] = zero;

  // staging offsets (halfs): row0 = tid>>3, sg = (tid&7)^((tid>>3)&7)
  const size_t off0 = (size_t)(tid >> 3) * K + ((tid & 7) ^ ((tid >> 3) & 7)) * 8;
  const size_t jstep = (size_t)32 * K;
  const unsigned short* Abase = A + (size_t)gr0 * K;
  const unsigned short* Bbase = Bt + (size_t)e * N * K + (size_t)col0 * K;

  const int sw = q ^ (m15 & 7);   // fragment slot base

  auto stage = [&](int buf, int kk) {
#pragma unroll
    for (int j = 0; j < 4; ++j) {
      async_ld16(Abase + off0 + j * jstep + kk, &ldsA[buf][(j * 256 + tid) * 8]);
      async_ld16(Bbase + off0 + j * jstep + kk, &ldsB[buf][(j * 256 + tid) * 8]);
    }
  };

  // prologue: fill buffer 0, drain, barrier
  stage(0, 0);
  __syncthreads();

  int cur = 0;
  for (int kk = 0; kk < K; kk += 64) {
    // issue next tile's loads first — they fly during the MFMA phase
    if (kk + 64 < K) stage(cur ^ 1, kk + 64);
#pragma unroll
    for (int ks2 = 0; ks2 < 2; ++ks2) {
      const int slot8 = (sw ^ (ks2 << 2)) * 8;
      bf16x8 af[4], bf[4];
#pragma unroll
      for (int mt = 0; mt < 4; ++mt)
        af[mt] = *(const bf16x8*)&ldsA[cur][(wr * 64 + mt * 16 + m15) * 64 + slot8];
#pragma unroll
      for (int nt = 0; nt < 4; ++nt)
        bf[nt] = *(const bf16x8*)&ldsB[cur][(wc * 64 + nt * 16 + m15) * 64 + slot8];
      __builtin_amdgcn_s_setprio(1);
#pragma unroll
      for (int mt = 0; mt < 4; ++mt)
#pragma unroll
        for (int nt = 0; nt < 4; ++nt)
          acc[mt][nt] = __builtin_amdgcn_mfma_f32_16x16x32_bf16(
              af[mt], bf[nt], acc[mt][nt], 0, 0, 0);
      __builtin_amdgcn_s_setprio(0);
    }
    // one barrier per K-step: implicit vmcnt(0) waits for the NEXT tile's
    // loads (issued above, latency covered by the 32 MFMAs) + all waves done
    // reading buf[cur] -> safe to overwrite it next iteration.
    __syncthreads();
    cur ^= 1;
  }

  // epilogue: C/D layout col=lane&15, row=q*4+i
#pragma unroll
  for (int nt = 0; nt < 4; ++nt) {
    const int c = col0 + wc * 64 + nt * 16 + m15;
    const float bv = bias[(size_t)e * N + c];
#pragma unroll
    for (int mt = 0; mt < 4; ++mt) {
      const size_t rbase = (size_t)(gr0 + wr * 64 + mt * 16 + q * 4);
      if (RELU) {
        unsigned short* Cp = (unsigned short*)Cout;
#pragma unroll
        for (int i = 0; i < 4; ++i)
          Cp[(rbase + i) * N + c] = f2bf(fmaxf(acc[mt][nt][i] + bv, 0.f));
      } else {
        float* Cp = (float*)Cout;
#pragma unroll
        for (int i = 0; i < 4; ++i)
          Cp[(rbase + i) * N + c] = acc[mt][nt][i] + bv;
      }
    }
  }
}

__global__ __launch_bounds__(256) void combine_kernel(
    const float* __restrict__ y, const int* __restrict__ pair_slot,
    const float* __restrict__ out_w, float* __restrict__ out)
{
  const int gid = blockIdx.x * 256 + threadIdx.x;
  if (gid >= TOKENS * (D_MODEL / 4)) return;
  const int t = gid >> 8;
  const int qd = gid & 255;
  const float w0 = out_w[t * 2 + 0], w1 = out_w[t * 2 + 1];
  const int p0 = pair_slot[t * 2 + 0], p1 = pair_slot[t * 2 + 1];
  const float4 a = *(const float4*)(y + (size_t)p0 * D_MODEL + qd * 4);
  const float4 b = *(const float4*)(y + (size_t)p1 * D_MODEL + qd * 4);
  float4 o;
  o.x = w0 * a.x + w1 * b.x;
  o.y = w0 * a.y + w1 * b.y;
  o.z = w0 * a.z + w1 * b.z;
  o.w = w0 * a.w + w1 * b.w;
  *(float4*)(out + (size_t)t * D_MODEL + qd * 4) = o;
}

extern "C" void kernel_launch(void* const* d_in, const int* in_sizes, int n_in,
                              void* d_out, int out_size, void* d_ws, size_t ws_size,
                              hipStream_t stream)
{
  (void)in_sizes; (void)n_in; (void)out_size; (void)ws_size;
  const float* x  = (const float*)d_in[0];
  const float* gw = (const float*)d_in[1];
  const float* w1 = (const float*)d_in[2];
  const float* b1 = (const float*)d_in[3];
  const float* w2 = (const float*)d_in[4];
  const float* b2 = (const float*)d_in[5];

  float* out        = (float*)d_out;
  float* out_logits = out + (size_t)TOKENS * D_MODEL;
  float* out_idx    = out_logits + (size_t)TOKENS * NEXP;
  float* out_w      = out_idx + (size_t)TOKENS * 2;

  int* wsI       = (int*)d_ws;
  int* po        = wsI + 16;
  int* tok_list  = wsI + 512;
  int* pair_slot = wsI + 10240;
  unsigned short* xg  = (unsigned short*)((char*)d_ws + (1 << 17));
  unsigned short* w1t = xg  + (size_t)SLOTSP * D_MODEL;
  unsigned short* w2t = w1t + (size_t)NEXP * D_FF * D_MODEL;
  unsigned short* h   = w2t + (size_t)NEXP * D_MODEL * D_FF;
  float*          y   = (float*)(h + (size_t)SLOTSP * D_FF);

  init_kernel<<<SLOTSP / 256, 256, 0, stream>>>(tok_list);
  router_kernel<<<TOKENS / 4, 256, 0, stream>>>(x, gw, out_logits, out_idx, out_w);
  count_offsets_kernel<<<1, 256, 0, stream>>>(out_idx, wsI);
  scatter_kernel<<<SLOTS / 256, 256, 0, stream>>>(out_idx, wsI + 8, po, pair_slot, tok_list);
  gather_cvt<<<SLOTSP * 128 / 256, 256, 0, stream>>>(x, tok_list, xg);
  transpose_cvt<<<dim3(D_FF / 64, D_MODEL / 64, NEXP), 256, 0, stream>>>(w1, w1t, D_MODEL, D_FF);
  transpose_cvt<<<dim3(D_MODEL / 64, D_FF / 64, NEXP), 256, 0, stream>>>(w2, w2t, D_FF, D_MODEL);
  gemm_mfma<1><<<dim3(D_FF / 128, 72, 1), 256, 0, stream>>>(
      xg, w1t, b1, (void*)h, wsI, D_MODEL, D_FF);
  gemm_mfma<0><<<dim3(D_MODEL / 128, 72, 1), 256, 0, stream>>>(
      h, w2t, b2, (void*)y, wsI, D_FF, D_MODEL);
  combine_kernel<<<(TOKENS * D_MODEL / 4) / 256, 256, 0, stream>>>(
      y, pair_slot, out_w, out);
}

// Round 2
// 594.756 us; speedup vs baseline: 1.1087x; 1.1021x over previous
//
#include <hip/hip_runtime.h>
#include <cstdint>
#include <cstddef>

// MoE layer, MI355X. Round 6: single-buffered 32KB GEMM (restores 5 blocks/CU
// co-residency — the m97-structure's latency-hiding mechanism) + XCD swizzle
// kept (FETCH 315->122MB proven) + split-K x2 for GEMM2 (grid 576->1152,
// K=2048/block, f32 partials aliased over xg/w1t, combine sums partials).
// T=4096, D=1024, F=4096, E=8, top-2. Padded slots: 9216.

#define D_MODEL 1024
#define D_FF    4096
#define NEXP    8
#define TOKENS  4096
#define SLOTS   8192
#define SLOTSP  9216

typedef __bf16 bf16x8 __attribute__((ext_vector_type(8)));
typedef float  f32x4  __attribute__((ext_vector_type(4)));

static __device__ __forceinline__ unsigned short f2bf(float f) {
  unsigned int u = __float_as_uint(f);
  u += 0x7fffu + ((u >> 16) & 1u);   // RNE
  return (unsigned short)(u >> 16);
}

static __device__ __forceinline__ void async_ld16(const void* g, void* l) {
  __builtin_amdgcn_global_load_lds(
      (const __attribute__((address_space(1))) void*)g,
      (__attribute__((address_space(3))) void*)l, 16, 0, 0);
}

// ---------------- setup kernels ----------------

__global__ void init_kernel(int* __restrict__ tok_list) {
  const int g = blockIdx.x * 256 + threadIdx.x;
  if (g < SLOTSP) tok_list[g] = -1;
}

// one wave per token; no atomics
__global__ __launch_bounds__(256) void router_kernel(
    const float* __restrict__ x, const float* __restrict__ gw,
    float* __restrict__ out_logits, float* __restrict__ out_idx,
    float* __restrict__ out_w)
{
  const int w = threadIdx.x >> 6, lane = threadIdx.x & 63;
  const int t = blockIdx.x * 4 + w;
  float p[NEXP];
#pragma unroll
  for (int e = 0; e < NEXP; ++e) p[e] = 0.f;
  const float* xr = x + (size_t)t * D_MODEL;
#pragma unroll 4
  for (int i = 0; i < D_MODEL / 64; ++i) {
    const int d = i * 64 + lane;
    const float xv = xr[d];
    const float* g = gw + (size_t)d * NEXP;
#pragma unroll
    for (int e = 0; e < NEXP; ++e) p[e] += xv * g[e];
  }
#pragma unroll
  for (int e = 0; e < NEXP; ++e) {
#pragma unroll
    for (int s = 1; s < 64; s <<= 1) p[e] += __shfl_xor(p[e], s, 64);
  }
  if (lane == 0) {
    int i0 = 0;
#pragma unroll
    for (int e = 1; e < NEXP; ++e) if (p[e] > p[i0]) i0 = e;
    int i1 = (i0 == 0) ? 1 : 0;
#pragma unroll
    for (int e = 0; e < NEXP; ++e)
      if (e != i0 && p[e] > p[i1]) i1 = e;
    const float w0 = 1.f / (1.f + __expf(p[i1] - p[i0]));
#pragma unroll
    for (int e = 0; e < NEXP; ++e) out_logits[(size_t)t * NEXP + e] = p[e];
    out_idx[t * 2 + 0] = (float)i0;
    out_idx[t * 2 + 1] = (float)i1;
    out_w[t * 2 + 0] = w0;
    out_w[t * 2 + 1] = 1.f - w0;
  }
}

// single block: histogram + padded offsets + block map + zero cursors
// wsI: [8..16)=cursor [16..25)=po [25]=nb [32..104)=blk_e [128..200)=blk_gr0
__global__ __launch_bounds__(256) void count_offsets_kernel(
    const float* __restrict__ out_idx, int* __restrict__ wsI)
{
  __shared__ int hist[NEXP];
  const int tid = threadIdx.x;
  if (tid < NEXP) hist[tid] = 0;
  if (tid < NEXP) wsI[8 + tid] = 0;   // cursors
  __syncthreads();
  int c[NEXP];
#pragma unroll
  for (int e = 0; e < NEXP; ++e) c[e] = 0;
  for (int p = tid * 32; p < tid * 32 + 32; ++p) c[(int)out_idx[p]]++;
#pragma unroll
  for (int e = 0; e < NEXP; ++e) if (c[e]) atomicAdd(&hist[e], c[e]);
  __syncthreads();
  if (tid == 0) {
    int s = 0, nb = 0;
    for (int e = 0; e < NEXP; ++e) {
      wsI[16 + e] = s;
      const int nblk = (hist[e] + 127) >> 7;
      for (int j = 0; j < nblk; ++j) {
        wsI[32 + nb] = e;
        wsI[128 + nb] = s + j * 128;
        ++nb;
      }
      s += nblk << 7;
    }
    wsI[16 + NEXP] = s;
    wsI[25] = nb;
  }
}

// ballot-aggregated per-wave atomics (~8 per wave instead of 64)
__global__ void scatter_kernel(const float* __restrict__ out_idx,
                               int* __restrict__ cursor,
                               const int* __restrict__ po,
                               int* __restrict__ pair_slot,
                               int* __restrict__ tok_list)
{
  const int p = blockIdx.x * 256 + threadIdx.x;
  const int lane = threadIdx.x & 63;
  const int e = (int)out_idx[p];
  int pos = 0;
#pragma unroll
  for (int e8 = 0; e8 < NEXP; ++e8) {
    const unsigned long long m = __ballot(e == e8);
    if (m) {
      const int leader = __ffsll((long long)m) - 1;
      int base = 0;
      if (lane == leader) base = atomicAdd(&cursor[e8], (int)__popcll(m));
      base = __shfl(base, leader, 64);
      if (e == e8)
        pos = po[e8] + base +
              (int)__popcll(m & ((1ull << lane) - 1ull));
    }
  }
  tok_list[pos] = p >> 1;
  pair_slot[p] = pos;
}

// gather x rows into slot order, f32 -> bf16
__global__ __launch_bounds__(256) void gather_cvt(
    const float* __restrict__ x, const int* __restrict__ tok_list,
    unsigned short* __restrict__ xg)
{
  const int gid = blockIdx.x * 256 + threadIdx.x;
  const int row = gid >> 7, seg = gid & 127;
  const int tok = tok_list[row];
  if (tok < 0) return;
  const float* src = x + (size_t)tok * D_MODEL + seg * 8;
  const float4 a = *(const float4*)(src);
  const float4 b = *(const float4*)(src + 4);
  ushort4 lo = make_ushort4(f2bf(a.x), f2bf(a.y), f2bf(a.z), f2bf(a.w));
  ushort4 hi = make_ushort4(f2bf(b.x), f2bf(b.y), f2bf(b.z), f2bf(b.w));
  unsigned short* d = xg + (size_t)row * D_MODEL + seg * 8;
  *(ushort4*)(d) = lo;
  *(ushort4*)(d + 4) = hi;
}

// src [E][K][N] f32 -> dst [E][N][K] bf16, 64x64 LDS-tiled
__global__ __launch_bounds__(256) void transpose_cvt(
    const float* __restrict__ src, unsigned short* __restrict__ dst,
    int K, int N)
{
  const int e = blockIdx.z;
  const int n0 = blockIdx.x * 64;
  const int k0 = blockIdx.y * 64;
  __shared__ float t[64][65];
  const int c4 = (threadIdx.x & 15) * 4;
  const int r  = threadIdx.x >> 4;
  const float* s = src + (size_t)e * K * N + (size_t)k0 * N + n0;
#pragma unroll
  for (int i = 0; i < 4; ++i) {
    const float4 v = *(const float4*)(s + (size_t)(r + 16 * i) * N + c4);
    t[r + 16 * i][c4 + 0] = v.x;
    t[r + 16 * i][c4 + 1] = v.y;
    t[r + 16 * i][c4 + 2] = v.z;
    t[r + 16 * i][c4 + 3] = v.w;
  }
  __syncthreads();
  unsigned short* d = dst + (size_t)e * N * K + (size_t)n0 * K + k0;
#pragma unroll
  for (int i = 0; i < 4; ++i) {
    const int n = r + 16 * i;
    ushort4 v;
    v.x = f2bf(t[c4 + 0][n]);
    v.y = f2bf(t[c4 + 1][n]);
    v.z = f2bf(t[c4 + 2][n]);
    v.w = f2bf(t[c4 + 3][n]);
    *(ushort4*)(d + (size_t)n * K + c4) = v;
  }
}

// ---------------- MFMA grouped GEMM, BK=64, single-buffer, split-K ----------------
// LDS layout: 128 rows x 8 segs(16B); data seg s of row r lives at slot s^(r&7).
// Staging: thread tid, chunk j: linear slot (j*256+tid) -> row=(..)>>3,
// s_lds=(..)&7, s_glob = s_lds ^ (row&7).
// Fragment: seg = ks2*4+q -> slot = (q ^ (m15&7)) ^ (ks2*4).
// 32KB LDS -> 5 blocks/CU co-resident (the latency-hiding mechanism).
// Split-K via blockIdx.z: each split covers K/gridDim.z, writes its own
// partial output plane (f32); bias added only by split 0. RELU never split.
template <int RELU>
__global__ __launch_bounds__(256) void gemm_mfma(
    const unsigned short* __restrict__ A, const unsigned short* __restrict__ Bt,
    const float* __restrict__ bias, void* __restrict__ Cout,
    const int* __restrict__ wsI, int K, int N)
{
  // bijective XCD-aware swizzle within each z-slice (nwg per slice % 8 == 0:
  // 2304 for GEMM1, 576 for GEMM2).
  const int gx = gridDim.x;
  const int nwg = gx * gridDim.y;
  const int cpx = nwg >> 3;
  int f = blockIdx.y * gx + blockIdx.x;
  f = (f & 7) * cpx + (f >> 3);
  const int bx = f % gx;
  const int by = f / gx;

  if (by >= wsI[25]) return;
  const int e   = wsI[32 + by];
  const int gr0 = wsI[128 + by];
  const int col0 = bx * 128;

  const int klen = K / gridDim.z;
  const int kbeg = blockIdx.z * klen;
  const int kend = kbeg + klen;

  __shared__ unsigned short ldsA[128 * 64];
  __shared__ unsigned short ldsB[128 * 64];

  const int tid = threadIdx.x;
  const int lane = tid & 63;
  const int w = tid >> 6;
  const int wr = w >> 1, wc = w & 1;
  const int m15 = lane & 15, q = lane >> 4;

  f32x4 zero = {0.f, 0.f, 0.f, 0.f};
  f32x4 acc[4][4];
#pragma unroll
  for (int mt = 0; mt < 4; ++mt)
#pragma unroll
    for (int nt = 0; nt < 4; ++nt) acc[mt][nt] = zero;

  // staging offsets (halfs): row0 = tid>>3, sg = (tid&7)^((tid>>3)&7)
  const size_t off0 = (size_t)(tid >> 3) * K + ((tid & 7) ^ ((tid >> 3) & 7)) * 8;
  const size_t jstep = (size_t)32 * K;
  const unsigned short* Abase = A + (size_t)gr0 * K;
  const unsigned short* Bbase = Bt + (size_t)e * N * K + (size_t)col0 * K;

  const int sw = q ^ (m15 & 7);   // fragment slot base

  for (int kk = kbeg; kk < kend; kk += 64) {
#pragma unroll
    for (int j = 0; j < 4; ++j) {
      async_ld16(Abase + off0 + j * jstep + kk, &ldsA[(j * 256 + tid) * 8]);
      async_ld16(Bbase + off0 + j * jstep + kk, &ldsB[(j * 256 + tid) * 8]);
    }
    __syncthreads();
#pragma unroll
    for (int ks2 = 0; ks2 < 2; ++ks2) {
      const int slot8 = (sw ^ (ks2 << 2)) * 8;
      bf16x8 af[4], bf[4];
#pragma unroll
      for (int mt = 0; mt < 4; ++mt)
        af[mt] = *(const bf16x8*)&ldsA[(wr * 64 + mt * 16 + m15) * 64 + slot8];
#pragma unroll
      for (int nt = 0; nt < 4; ++nt)
        bf[nt] = *(const bf16x8*)&ldsB[(wc * 64 + nt * 16 + m15) * 64 + slot8];
#pragma unroll
      for (int mt = 0; mt < 4; ++mt)
#pragma unroll
        for (int nt = 0; nt < 4; ++nt)
          acc[mt][nt] = __builtin_amdgcn_mfma_f32_16x16x32_bf16(
              af[mt], bf[nt], acc[mt][nt], 0, 0, 0);
    }
    __syncthreads();
  }

  // epilogue: C/D layout col=lane&15, row=q*4+i
  const size_t zoff = (size_t)blockIdx.z * SLOTSP * (size_t)N;
#pragma unroll
  for (int nt = 0; nt < 4; ++nt) {
    const int c = col0 + wc * 64 + nt * 16 + m15;
    const float bv = (blockIdx.z == 0) ? bias[(size_t)e * N + c] : 0.f;
#pragma unroll
    for (int mt = 0; mt < 4; ++mt) {
      const size_t rbase = (size_t)(gr0 + wr * 64 + mt * 16 + q * 4);
      if (RELU) {
        unsigned short* Cp = (unsigned short*)Cout;
#pragma unroll
        for (int i = 0; i < 4; ++i)
          Cp[(rbase + i) * N + c] = f2bf(fmaxf(acc[mt][nt][i] + bv, 0.f));
      } else {
        float* Cp = (float*)Cout + zoff;
#pragma unroll
        for (int i = 0; i < 4; ++i)
          Cp[(rbase + i) * N + c] = acc[mt][nt][i] + bv;
      }
    }
  }
}

// sums the two split-K partial planes of y
__global__ __launch_bounds__(256) void combine_kernel(
    const float* __restrict__ y, const int* __restrict__ pair_slot,
    const float* __restrict__ out_w, float* __restrict__ out)
{
  const int gid = blockIdx.x * 256 + threadIdx.x;
  if (gid >= TOKENS * (D_MODEL / 4)) return;
  const int t = gid >> 8;
  const int qd = gid & 255;
  const float w0 = out_w[t * 2 + 0], w1 = out_w[t * 2 + 1];
  const int p0 = pair_slot[t * 2 + 0], p1 = pair_slot[t * 2 + 1];
  const float* y1 = y + (size_t)SLOTSP * D_MODEL;
  const float4 a0 = *(const float4*)(y  + (size_t)p0 * D_MODEL + qd * 4);
  const float4 a1 = *(const float4*)(y1 + (size_t)p0 * D_MODEL + qd * 4);
  const float4 b0 = *(const float4*)(y  + (size_t)p1 * D_MODEL + qd * 4);
  const float4 b1 = *(const float4*)(y1 + (size_t)p1 * D_MODEL + qd * 4);
  float4 o;
  o.x = w0 * (a0.x + a1.x) + w1 * (b0.x + b1.x);
  o.y = w0 * (a0.y + a1.y) + w1 * (b0.y + b1.y);
  o.z = w0 * (a0.z + a1.z) + w1 * (b0.z + b1.z);
  o.w = w0 * (a0.w + a1.w) + w1 * (b0.w + b1.w);
  *(float4*)(out + (size_t)t * D_MODEL + qd * 4) = o;
}

extern "C" void kernel_launch(void* const* d_in, const int* in_sizes, int n_in,
                              void* d_out, int out_size, void* d_ws, size_t ws_size,
                              hipStream_t stream)
{
  (void)in_sizes; (void)n_in; (void)out_size; (void)ws_size;
  const float* x  = (const float*)d_in[0];
  const float* gw = (const float*)d_in[1];
  const float* w1 = (const float*)d_in[2];
  const float* b1 = (const float*)d_in[3];
  const float* w2 = (const float*)d_in[4];
  const float* b2 = (const float*)d_in[5];

  float* out        = (float*)d_out;
  float* out_logits = out + (size_t)TOKENS * D_MODEL;
  float* out_idx    = out_logits + (size_t)TOKENS * NEXP;
  float* out_w      = out_idx + (size_t)TOKENS * 2;

  int* wsI       = (int*)d_ws;
  int* po        = wsI + 16;
  int* tok_list  = wsI + 512;
  int* pair_slot = wsI + 10240;
  unsigned short* xg  = (unsigned short*)((char*)d_ws + (1 << 17));
  unsigned short* w1t = xg  + (size_t)SLOTSP * D_MODEL;
  unsigned short* w2t = w1t + (size_t)NEXP * D_FF * D_MODEL;
  unsigned short* h   = w2t + (size_t)NEXP * D_MODEL * D_FF;
  // split-K partials: 2 x 37.75MB f32, aliased over xg(18.9MB)+w1t(64MB) —
  // both dead after GEMM1, region untouched by h/w2t.
  float*          y   = (float*)xg;

  init_kernel<<<SLOTSP / 256, 256, 0, stream>>>(tok_list);
  router_kernel<<<TOKENS / 4, 256, 0, stream>>>(x, gw, out_logits, out_idx, out_w);
  count_offsets_kernel<<<1, 256, 0, stream>>>(out_idx, wsI);
  scatter_kernel<<<SLOTS / 256, 256, 0, stream>>>(out_idx, wsI + 8, po, pair_slot, tok_list);
  gather_cvt<<<SLOTSP * 128 / 256, 256, 0, stream>>>(x, tok_list, xg);
  transpose_cvt<<<dim3(D_FF / 64, D_MODEL / 64, NEXP), 256, 0, stream>>>(w1, w1t, D_MODEL, D_FF);
  transpose_cvt<<<dim3(D_MODEL / 64, D_FF / 64, NEXP), 256, 0, stream>>>(w2, w2t, D_FF, D_MODEL);
  gemm_mfma<1><<<dim3(D_FF / 128, 72, 1), 256, 0, stream>>>(
      xg, w1t, b1, (void*)h, wsI, D_MODEL, D_FF);
  gemm_mfma<0><<<dim3(D_MODEL / 128, 72, 2), 256, 0, stream>>>(
      h, w2t, b2, (void*)y, wsI, D_FF, D_MODEL);
  combine_kernel<<<(TOKENS * D_MODEL / 4) / 256, 256, 0, stream>>>(
      y, pair_slot, out_w, out);
}